// Round 2
// baseline (117.862 us; speedup 1.0000x reference)
//
#include <hip/hip_runtime.h>
#include <math.h>

// LocalAttention: B=2, T=2048, C=512, WINDOW=32
#define BB 2
#define TT 2048
#define CC 512
#define WIN 32
#define WSZ 63            // 2*WIN-1
#define MM (BB * TT)      // 4096

typedef __attribute__((ext_vector_type(8))) short short8;
typedef __attribute__((ext_vector_type(4))) float floatx4;

__device__ inline unsigned short bf16_rn(float f) {
  unsigned u = __builtin_bit_cast(unsigned, f);
  u += 0x7fff + ((u >> 16) & 1);
  return (unsigned short)(u >> 16);
}
__device__ inline unsigned pack_bf16x2(float lo, float hi) {
  return (unsigned)bf16_rn(lo) | ((unsigned)bf16_rn(hi) << 16);
}

// ---------------------------------------------------------------------------
// Pre-convert fp32 inputs -> bf16 (x, w_qkv, w_proj). 8 elems/thread.
// ---------------------------------------------------------------------------
#define NX  (MM * CC)          // 2097152
#define NWQ (3 * CC * CC)      // 786432
#define NWP (CC * CC)          // 262144

__global__ __launch_bounds__(256) void convert_bf16(
    const float* __restrict__ x, const float* __restrict__ wq,
    const float* __restrict__ wp, ushort* __restrict__ xb,
    ushort* __restrict__ wqb, ushort* __restrict__ wpb) {
  const size_t e = ((size_t)blockIdx.x * 256 + threadIdx.x) * 8;
  const float* src;
  ushort* dst;
  size_t off;
  if (e < NX) { src = x; dst = xb; off = e; }
  else if (e < NX + NWQ) { src = wq; dst = wqb; off = e - NX; }
  else { src = wp; dst = wpb; off = e - NX - NWQ; }
  float4 v0 = ((const float4*)(src + off))[0];
  float4 v1 = ((const float4*)(src + off))[1];
  uint4 o;
  o.x = pack_bf16x2(v0.x, v0.y);
  o.y = pack_bf16x2(v0.z, v0.w);
  o.z = pack_bf16x2(v1.x, v1.y);
  o.w = pack_bf16x2(v1.z, v1.w);
  *(uint4*)(dst + off) = o;
}

// ---------------------------------------------------------------------------
// Barrier-light NT GEMM: C[m,n] = sum_k A[m,k]*B[n,k] + bias[n], K=512 fixed.
// Block = 128 x 64. B-panel (64 n x 256 k) staged in LDS once per k-half ->
// only 3 barriers per block, NO per-K-step barrier/drain. A fragments are
// loaded directly from global (L1/L2-hot). 4 waves, each owns 32 m-rows
// and the full 64-n range.
// V path (n0 >= 1024): tile is bias-added, packed to bf16, transposed
// through LDS, and written as coalesced 256B rows of VT[n][m].
// ---------------------------------------------------------------------------
#define PSTR 264   // B-panel k-stride (elems); 528B rows -> 2-way banked frag reads
#define VSTR 136   // V-transpose m-stride (elems); 16B-aligned rows, odd granules

__global__ __launch_bounds__(256) void gemm_qkv(
    const ushort* __restrict__ A, const ushort* __restrict__ B,
    const float* __restrict__ bias, ushort* __restrict__ C,
    ushort* __restrict__ VT, int M, int N) {
  constexpr int MIW = 2;                          // m-frags per wave
  __shared__ __align__(16) ushort Bs[64 * PSTR];  // 33792 B; Vt aliases below

  const int tid = threadIdx.x;
  const int lane = tid & 63;
  const int wave = tid >> 6;
  const int m0 = blockIdx.y * 128;
  const int n0 = blockIdx.x * 64;
  const int wm = wave * 32;
  const int mlane = lane & 15, quad = lane >> 4;

  floatx4 acc[MIW][4];
#pragma unroll
  for (int i = 0; i < MIW; ++i)
#pragma unroll
    for (int j = 0; j < 4; ++j) acc[i][j] = (floatx4){0.f, 0.f, 0.f, 0.f};

  for (int h = 0; h < 2; ++h) {
    if (h) __syncthreads();
    // stage B panel half: 64 rows x 256 k = 2048 uint4, coalesced
#pragma unroll
    for (int i = 0; i < 8; ++i) {
      const int idx = tid + 256 * i;
      const int r = idx >> 5, kc = (idx & 31) * 8;
      *(uint4*)(&Bs[r * PSTR + kc]) =
          *(const uint4*)(B + (size_t)(n0 + r) * CC + h * 256 + kc);
    }
    __syncthreads();
#pragma unroll
    for (int ks = 0; ks < 8; ++ks) {
      short8 bfr[4];
#pragma unroll
      for (int ni = 0; ni < 4; ++ni)
        bfr[ni] = *(const short8*)(&Bs[(ni * 16 + mlane) * PSTR + ks * 32 + quad * 8]);
#pragma unroll
      for (int mi = 0; mi < MIW; ++mi) {
        short8 af = *(const short8*)(
            A + (size_t)(m0 + wm + mi * 16 + mlane) * CC + h * 256 + ks * 32 + quad * 8);
#pragma unroll
        for (int ni = 0; ni < 4; ++ni)
          acc[mi][ni] = __builtin_amdgcn_mfma_f32_16x16x32_bf16(af, bfr[ni], acc[mi][ni], 0, 0, 0);
      }
    }
  }

  // epilogue: D row = quad*4 + r (m), col = mlane (n)
  const bool vpath = (n0 >= 1024);
  if (!vpath) {
#pragma unroll
    for (int ni = 0; ni < 4; ++ni) {
      const int n = n0 + ni * 16 + mlane;
      const float bn = bias[n];
#pragma unroll
      for (int mi = 0; mi < MIW; ++mi) {
        const int mbase = m0 + wm + mi * 16 + quad * 4;
#pragma unroll
        for (int r = 0; r < 4; ++r)
          C[(size_t)(mbase + r) * N + n] = bf16_rn(acc[mi][ni][r] + bn);
      }
    }
  } else {
    // transpose through LDS, then coalesced VT[n][m] row writes
    ushort* Vt = Bs;  // alias; 64 x VSTR = 17408 B
    __syncthreads();
#pragma unroll
    for (int ni = 0; ni < 4; ++ni) {
      const int n_l = ni * 16 + mlane;
      const float bn = bias[n0 + n_l];
#pragma unroll
      for (int mi = 0; mi < MIW; ++mi) {
        const int m_l = wm + mi * 16 + quad * 4;
        ushort4 pk;
        pk.x = bf16_rn(acc[mi][ni][0] + bn);
        pk.y = bf16_rn(acc[mi][ni][1] + bn);
        pk.z = bf16_rn(acc[mi][ni][2] + bn);
        pk.w = bf16_rn(acc[mi][ni][3] + bn);
        *(ushort4*)(&Vt[n_l * VSTR + m_l]) = pk;
      }
    }
    __syncthreads();
#pragma unroll
    for (int i = 0; i < 4; ++i) {  // 64 rows x 16 uint4
      const int idx = tid + 256 * i;
      const int n_l = idx >> 4, mo = (idx & 15) * 8;
      *(uint4*)(VT + (size_t)(n0 - 1024 + n_l) * M + m0 + mo) =
          *(const uint4*)(&Vt[n_l * VSTR + mo]);
    }
  }
}

// ---------------------------------------------------------------------------
// Fused banded attention + output projection. Block = 16 tokens, grid 256
// (1 block/CU, XCD-bijective swizzle -> contiguous 512-token span per XCD).
// Phase 1: LDS-free MFMA attention (QK^T direct from global, softmax in LDS,
//   PV from vT) -> 16x512 bf16 tile kept in LDS (o_s).
// Phase 2: out = o_s @ w_proj.T + b_proj, fp32 written directly. w_proj bf16
//   is 512KB -> L2-resident on every XCD; adds ~128 MFMA/wave to a
//   latency-bound kernel (near-free) and deletes the gemm2 dispatch + the
//   4MB attn-buffer write + 4MB re-read + one launch boundary.
// o_s row stride 520 ushorts = 1040B: 16B-aligned rows; bank stride 4 ->
// 16-row frag reads are 2-way banked (free).
// OOB K/vT reads fault-safe via ws guards; garbage lands in P=0 positions.
// ---------------------------------------------------------------------------
#define ATILE 16
#define SLD 84    // S row stride (floats)
#define PLD 104   // P row stride (ushorts), odd granules -> conflict-free
#define OLD 520   // fused out-tile row stride (ushorts)

__global__ __launch_bounds__(256) void attn_proj(
    const ushort* __restrict__ qkv, const ushort* __restrict__ vT,
    const ushort* __restrict__ wp, const float* __restrict__ bproj,
    float* __restrict__ outp) {
  __shared__ __align__(16) float s_s[16 * SLD];
  __shared__ __align__(16) ushort p_s[16 * PLD];
  __shared__ __align__(16) ushort o_s[16 * OLD];

  const int tid = threadIdx.x;
  const int wave = tid >> 6, lane = tid & 63;
  const int mlane = lane & 15, quad = lane >> 4;
  // XCD-bijective swizzle: 256 blocks, 8 XCDs, 32 tiles each (contiguous)
  const int tile = ((blockIdx.x & 7) << 5) | (blockIdx.x >> 3);
  const int bt0 = tile * ATILE;
  const int b = bt0 / TT, t0 = bt0 % TT;
  const ushort* qbase = qkv + (size_t)b * TT * (3 * CC);

  // ---- phase 1a: S = Q K^T over the 80-key band
  const ushort* qrow  = qbase + (ptrdiff_t)(t0 + mlane) * (3 * CC);
  const ushort* krow0 = qbase + (ptrdiff_t)(t0 - 32 + wave * 16 + mlane) * (3 * CC) + CC;
  const ushort* krow1 = qbase + (ptrdiff_t)(t0 - 32 + 64 + mlane) * (3 * CC) + CC;
  floatx4 sacc0 = (floatx4){0.f, 0.f, 0.f, 0.f};
  floatx4 sacc1 = (floatx4){0.f, 0.f, 0.f, 0.f};
#pragma unroll
  for (int ks = 0; ks < 16; ++ks) {
    short8 a  = *(const short8*)(qrow + ks * 32 + quad * 8);
    short8 b0 = *(const short8*)(krow0 + ks * 32 + quad * 8);
    sacc0 = __builtin_amdgcn_mfma_f32_16x16x32_bf16(a, b0, sacc0, 0, 0, 0);
    if (wave == 0) {
      short8 b1 = *(const short8*)(krow1 + ks * 32 + quad * 8);
      sacc1 = __builtin_amdgcn_mfma_f32_16x16x32_bf16(a, b1, sacc1, 0, 0, 0);
    }
  }

#pragma unroll
  for (int r = 0; r < 4; ++r)
    s_s[(quad * 4 + r) * SLD + wave * 16 + mlane] = sacc0[r];
  if (wave == 0) {
#pragma unroll
    for (int r = 0; r < 4; ++r)
      s_s[(quad * 4 + r) * SLD + 64 + mlane] = sacc1[r];
  }
  __syncthreads();

  // ---- phase 1b: masked softmax (one 16-lane group per row)
  {
    const int row = tid >> 4, li = tid & 15;
    const float inv_scale = 0.044194173824159216f;  // 512^-0.5
    float e[5];
    float mx = -INFINITY;
#pragma unroll
    for (int i = 0; i < 5; ++i) {
      const int r = li + 16 * i;
      const int j = r - 1 - row;
      const int src = t0 - 32 + r;
      const bool valid = (j >= 0) && (j < WSZ) && (src >= 0) && (src < TT);
      e[i] = valid ? s_s[row * SLD + r] * inv_scale : -INFINITY;
      mx = fmaxf(mx, e[i]);
    }
    mx = fmaxf(mx, __shfl_xor(mx, 1)); mx = fmaxf(mx, __shfl_xor(mx, 2));
    mx = fmaxf(mx, __shfl_xor(mx, 4)); mx = fmaxf(mx, __shfl_xor(mx, 8));
    float sum = 0.f;
#pragma unroll
    for (int i = 0; i < 5; ++i) {
      e[i] = (e[i] == -INFINITY) ? 0.f : __expf(e[i] - mx);
      sum += e[i];
    }
    sum += __shfl_xor(sum, 1); sum += __shfl_xor(sum, 2);
    sum += __shfl_xor(sum, 4); sum += __shfl_xor(sum, 8);
    const float rs = 1.f / sum;
#pragma unroll
    for (int i = 0; i < 5; ++i)
      p_s[row * PLD + li + 16 * i] = bf16_rn(e[i] * rs);
    if (li < 8) {
      p_s[row * PLD + 80 + li] = 0;
      p_s[row * PLD + 88 + li] = 0;
      p_s[row * PLD + 96 + li] = 0;
    }
  }
  __syncthreads();

  // ---- phase 1c: PV -> bf16 tile in LDS (o_s), 128 cols per wave
  const ptrdiff_t mcol0 = (ptrdiff_t)b * TT + t0 - 32;
#pragma unroll 2
  for (int nt8 = 0; nt8 < 8; ++nt8) {
    const int nt = wave * 8 + nt8;
    const ushort* vrow = vT + (ptrdiff_t)(nt * 16 + mlane) * MM + mcol0;
    floatx4 o = (floatx4){0.f, 0.f, 0.f, 0.f};
#pragma unroll
    for (int ks = 0; ks < 3; ++ks) {
      short8 a  = *(const short8*)(&p_s[mlane * PLD + ks * 32 + quad * 8]);
      short8 bv = *(const short8*)(vrow + ks * 32 + quad * 8);
      o = __builtin_amdgcn_mfma_f32_16x16x32_bf16(a, bv, o, 0, 0, 0);
    }
#pragma unroll
    for (int r = 0; r < 4; ++r)
      o_s[(quad * 4 + r) * OLD + nt * 16 + mlane] = bf16_rn(o[r]);
  }
  __syncthreads();

  // ---- phase 2: out = o_s @ w_proj.T + b_proj (fp32 direct)
  short8 afr[16];
#pragma unroll
  for (int ks = 0; ks < 16; ++ks)
    afr[ks] = *(const short8*)(&o_s[mlane * OLD + ks * 32 + quad * 8]);
#pragma unroll
  for (int nt2 = 0; nt2 < 8; ++nt2) {
    const int n = wave * 128 + nt2 * 16 + mlane;
    const ushort* wrow = wp + (size_t)n * CC;
    floatx4 acc = (floatx4){0.f, 0.f, 0.f, 0.f};
#pragma unroll
    for (int ks = 0; ks < 16; ++ks) {
      short8 bfr = *(const short8*)(wrow + ks * 32 + quad * 8);
      acc = __builtin_amdgcn_mfma_f32_16x16x32_bf16(afr[ks], bfr, acc, 0, 0, 0);
    }
    const float bn = bproj[n];
#pragma unroll
    for (int r = 0; r < 4; ++r)
      outp[(size_t)(bt0 + quad * 4 + r) * CC + n] = acc[r] + bn;
  }
}

// ---------------------------------------------------------------------------
extern "C" void kernel_launch(void* const* d_in, const int* in_sizes, int n_in,
                              void* d_out, int out_size, void* d_ws, size_t ws_size,
                              hipStream_t stream) {
  const float* x      = (const float*)d_in[0];
  const float* w_qkv  = (const float*)d_in[1];
  const float* b_qkv  = (const float*)d_in[2];
  const float* w_proj = (const float*)d_in[3];
  const float* b_proj = (const float*)d_in[4];
  float* outp = (float*)d_out;

  // ws layout (ushorts). 256 KB front guard absorbs attn's src<0 K-reads;
  // guard buffer right after qkv absorbs src>=TT K-read overruns.
  ushort* base  = (ushort*)d_ws;
  ushort* qkv   = base + 131072;                   // MM x 1536 (V third unused)
  ushort* guard = qkv + (size_t)MM * 3 * CC;       // MM x 512 (K-overrun guard)
  ushort* xb    = guard + (size_t)MM * CC;         // MM x 512
  ushort* wqb   = xb + (size_t)NX;                 // 1536 x 512
  ushort* wpb   = wqb + (size_t)NWQ;               // 512 x 512
  ushort* vTg   = wpb + (size_t)NWP;               // guard(64) + 512 x 4096 + guard(64)
  ushort* vT    = vTg + 64;
  (void)guard;

  // 0) convert fp32 inputs to bf16
  convert_bf16<<<(NX + NWQ + NWP) / (256 * 8), 256, 0, stream>>>(x, w_qkv, w_proj, xb, wqb, wpb);
  // 1) qkv = x @ w_qkv.T + b_qkv -> Q,K bf16 rows; V written transposed to vT
  {
    dim3 grid((3 * CC) / 64, MM / 128);  // 24 x 32 = 768 blocks
    gemm_qkv<<<grid, 256, 0, stream>>>(xb, wqb, b_qkv, qkv, vT, MM, 3 * CC);
  }
  // 2) fused banded attention + output projection -> fp32 out
  attn_proj<<<MM / ATILE, 256, 0, stream>>>(qkv, vT, wpb, b_proj, outp);
}

// Round 3
// 110.637 us; speedup vs baseline: 1.0653x; 1.0653x over previous
//
#include <hip/hip_runtime.h>
#include <math.h>

// LocalAttention: B=2, T=2048, C=512, WINDOW=32
#define BB 2
#define TT 2048
#define CC 512
#define WIN 32
#define WSZ 63            // 2*WIN-1
#define MM (BB * TT)      // 4096

typedef __attribute__((ext_vector_type(8))) short short8;
typedef __attribute__((ext_vector_type(4))) float floatx4;

__device__ inline unsigned short bf16_rn(float f) {
  unsigned u = __builtin_bit_cast(unsigned, f);
  u += 0x7fff + ((u >> 16) & 1);
  return (unsigned short)(u >> 16);
}
__device__ inline unsigned pack_bf16x2(float lo, float hi) {
  return (unsigned)bf16_rn(lo) | ((unsigned)bf16_rn(hi) << 16);
}

// ---------------------------------------------------------------------------
// Pre-convert fp32 inputs -> bf16 (x, w_qkv, w_proj). 8 elems/thread.
// ---------------------------------------------------------------------------
#define NX  (MM * CC)          // 2097152
#define NWQ (3 * CC * CC)      // 786432
#define NWP (CC * CC)          // 262144

__global__ __launch_bounds__(256) void convert_bf16(
    const float* __restrict__ x, const float* __restrict__ wq,
    const float* __restrict__ wp, ushort* __restrict__ xb,
    ushort* __restrict__ wqb, ushort* __restrict__ wpb) {
  const size_t e = ((size_t)blockIdx.x * 256 + threadIdx.x) * 8;
  const float* src;
  ushort* dst;
  size_t off;
  if (e < NX) { src = x; dst = xb; off = e; }
  else if (e < NX + NWQ) { src = wq; dst = wqb; off = e - NX; }
  else { src = wp; dst = wpb; off = e - NX - NWQ; }
  float4 v0 = ((const float4*)(src + off))[0];
  float4 v1 = ((const float4*)(src + off))[1];
  uint4 o;
  o.x = pack_bf16x2(v0.x, v0.y);
  o.y = pack_bf16x2(v0.z, v0.w);
  o.z = pack_bf16x2(v1.x, v1.y);
  o.w = pack_bf16x2(v1.z, v1.w);
  *(uint4*)(dst + off) = o;
}

// ---------------------------------------------------------------------------
// Barrier-light NT GEMM: C[m,n] = sum_k A[m,k]*B[n,k] + bias[n], K=512 fixed.
// Block = BM x 64. B-panel (64 n x 256 k) staged in LDS once per k-half ->
// only 3 barriers per block, NO per-K-step barrier/drain. A fragments are
// loaded directly from global (L1/L2-hot). 4 waves, each owns BM/4 m-rows
// and the full 64-n range.
// XCD-chunked block swizzle (bijective: grid%8==0 for both callers): each
// XCD gets a contiguous run of m-panels x all n-columns, so its A-panel
// (512KB) + B matrix (<=1.5MB) fit the 4MB per-XCD L2 -> A re-reads across
// n-blocks become L2 hits instead of L3.
// V path (VT != nullptr && n0 >= 1024): tile is bias-added, packed to bf16,
// transposed through LDS, and written as coalesced 256B rows of VT[n][m].
// ---------------------------------------------------------------------------
#define PSTR 264   // B-panel k-stride (elems); 528B rows -> 2-way banked frag reads
#define VSTR 136   // V-transpose m-stride (elems); 16B-aligned rows, odd granules

template <int BM, typename OT>
__global__ __launch_bounds__(256) void gemm_panel(
    const ushort* __restrict__ A, const ushort* __restrict__ B,
    const float* __restrict__ bias, OT* __restrict__ C,
    ushort* __restrict__ VT, int M, int N) {
  constexpr int MIW = BM / 64;                    // m-frags per wave (2 or 1)
  __shared__ __align__(16) ushort Bs[64 * PSTR];  // 33792 B; Vt aliases below

  const int tid = threadIdx.x;
  const int lane = tid & 63;
  const int wave = tid >> 6;
  // XCD-chunked bijective swizzle
  const int id  = blockIdx.y * gridDim.x + blockIdx.x;
  const int nbl = gridDim.x * gridDim.y;
  const int nid = (id & 7) * (nbl >> 3) + (id >> 3);
  const int bx  = nid % gridDim.x;
  const int by  = nid / gridDim.x;
  const int m0 = by * BM;
  const int n0 = bx * 64;
  const int wm = wave * (BM / 4);
  const int mlane = lane & 15, quad = lane >> 4;

  floatx4 acc[MIW][4];
#pragma unroll
  for (int i = 0; i < MIW; ++i)
#pragma unroll
    for (int j = 0; j < 4; ++j) acc[i][j] = (floatx4){0.f, 0.f, 0.f, 0.f};

  for (int h = 0; h < 2; ++h) {
    if (h) __syncthreads();
    // stage B panel half: 64 rows x 256 k = 2048 uint4, coalesced
#pragma unroll
    for (int i = 0; i < 8; ++i) {
      const int idx = tid + 256 * i;
      const int r = idx >> 5, kc = (idx & 31) * 8;
      *(uint4*)(&Bs[r * PSTR + kc]) =
          *(const uint4*)(B + (size_t)(n0 + r) * CC + h * 256 + kc);
    }
    __syncthreads();
#pragma unroll
    for (int ks = 0; ks < 8; ++ks) {
      short8 bfr[4];
#pragma unroll
      for (int ni = 0; ni < 4; ++ni)
        bfr[ni] = *(const short8*)(&Bs[(ni * 16 + mlane) * PSTR + ks * 32 + quad * 8]);
#pragma unroll
      for (int mi = 0; mi < MIW; ++mi) {
        short8 af = *(const short8*)(
            A + (size_t)(m0 + wm + mi * 16 + mlane) * CC + h * 256 + ks * 32 + quad * 8);
#pragma unroll
        for (int ni = 0; ni < 4; ++ni)
          acc[mi][ni] = __builtin_amdgcn_mfma_f32_16x16x32_bf16(af, bfr[ni], acc[mi][ni], 0, 0, 0);
      }
    }
  }

  // epilogue: D row = quad*4 + r (m), col = mlane (n)
  const bool vpath = (VT != nullptr) && (n0 >= 1024);
  if (!vpath) {
#pragma unroll
    for (int ni = 0; ni < 4; ++ni) {
      const int n = n0 + ni * 16 + mlane;
      const float bn = bias[n];
#pragma unroll
      for (int mi = 0; mi < MIW; ++mi) {
        const int mbase = m0 + wm + mi * 16 + quad * 4;
#pragma unroll
        for (int r = 0; r < 4; ++r) {
          float val = acc[mi][ni][r] + bn;
          if constexpr (sizeof(OT) == 2)
            ((ushort*)C)[(size_t)(mbase + r) * N + n] = bf16_rn(val);
          else
            ((float*)C)[(size_t)(mbase + r) * N + n] = val;
        }
      }
    }
  } else if constexpr (BM == 128) {
    // transpose through LDS, then coalesced VT[n][m] row writes
    ushort* Vt = Bs;  // alias; 64 x VSTR = 17408 B
    __syncthreads();
#pragma unroll
    for (int ni = 0; ni < 4; ++ni) {
      const int n_l = ni * 16 + mlane;
      const float bn = bias[n0 + n_l];
#pragma unroll
      for (int mi = 0; mi < MIW; ++mi) {
        const int m_l = wm + mi * 16 + quad * 4;
        ushort4 pk;
        pk.x = bf16_rn(acc[mi][ni][0] + bn);
        pk.y = bf16_rn(acc[mi][ni][1] + bn);
        pk.z = bf16_rn(acc[mi][ni][2] + bn);
        pk.w = bf16_rn(acc[mi][ni][3] + bn);
        *(ushort4*)(&Vt[n_l * VSTR + m_l]) = pk;
      }
    }
    __syncthreads();
#pragma unroll
    for (int i = 0; i < 4; ++i) {  // 64 rows x 16 uint4
      const int idx = tid + 256 * i;
      const int n_l = idx >> 4, mo = (idx & 15) * 8;
      *(uint4*)(VT + (size_t)(n0 - 1024 + n_l) * M + m0 + mo) =
          *(const uint4*)(&Vt[n_l * VSTR + mo]);
    }
  }
}

// ---------------------------------------------------------------------------
// LDS-free MFMA banded attention. Block = 16 tokens; the 16-row Q-tile needs
// a 16+62=78-key band <= the 80 columns computed. Grid 256 = 1 block/CU;
// XCD-bijective swizzle -> contiguous 512-token span per XCD (K-band/V-window
// overlaps between adjacent tiles are concurrent L2 hits).
// OOB reads fault-safe via ws guards; garbage lands in masked/P=0 positions.
// ---------------------------------------------------------------------------
#define ATILE 16
#define SLD 84    // S row stride (floats)
#define PLD 104   // P row stride (ushorts), odd granules -> conflict-free

__global__ __launch_bounds__(256) void attn_mfma(
    const ushort* __restrict__ qkv, const ushort* __restrict__ vT,
    ushort* __restrict__ out) {
  __shared__ __align__(16) float s_s[16 * SLD];
  __shared__ __align__(16) ushort p_s[16 * PLD];

  const int tid = threadIdx.x;
  const int wave = tid >> 6, lane = tid & 63;
  const int mlane = lane & 15, quad = lane >> 4;
  // XCD-bijective swizzle: 256 blocks, 8 XCDs, 32 tiles each (contiguous)
  const int tile = ((blockIdx.x & 7) << 5) | (blockIdx.x >> 3);
  const int bt0 = tile * ATILE;
  const int b = bt0 / TT, t0 = bt0 % TT;
  const ushort* qbase = qkv + (size_t)b * TT * (3 * CC);

  const ushort* qrow  = qbase + (ptrdiff_t)(t0 + mlane) * (3 * CC);
  const ushort* krow0 = qbase + (ptrdiff_t)(t0 - 32 + wave * 16 + mlane) * (3 * CC) + CC;
  const ushort* krow1 = qbase + (ptrdiff_t)(t0 - 32 + 64 + mlane) * (3 * CC) + CC;
  floatx4 sacc0 = (floatx4){0.f, 0.f, 0.f, 0.f};
  floatx4 sacc1 = (floatx4){0.f, 0.f, 0.f, 0.f};
#pragma unroll
  for (int ks = 0; ks < 16; ++ks) {
    short8 a  = *(const short8*)(qrow + ks * 32 + quad * 8);
    short8 b0 = *(const short8*)(krow0 + ks * 32 + quad * 8);
    sacc0 = __builtin_amdgcn_mfma_f32_16x16x32_bf16(a, b0, sacc0, 0, 0, 0);
    if (wave == 0) {
      short8 b1 = *(const short8*)(krow1 + ks * 32 + quad * 8);
      sacc1 = __builtin_amdgcn_mfma_f32_16x16x32_bf16(a, b1, sacc1, 0, 0, 0);
    }
  }

#pragma unroll
  for (int r = 0; r < 4; ++r)
    s_s[(quad * 4 + r) * SLD + wave * 16 + mlane] = sacc0[r];
  if (wave == 0) {
#pragma unroll
    for (int r = 0; r < 4; ++r)
      s_s[(quad * 4 + r) * SLD + 64 + mlane] = sacc1[r];
  }
  __syncthreads();

  {
    const int row = tid >> 4, li = tid & 15;
    const float inv_scale = 0.044194173824159216f;  // 512^-0.5
    float e[5];
    float mx = -INFINITY;
#pragma unroll
    for (int i = 0; i < 5; ++i) {
      const int r = li + 16 * i;
      const int j = r - 1 - row;
      const int src = t0 - 32 + r;
      const bool valid = (j >= 0) && (j < WSZ) && (src >= 0) && (src < TT);
      e[i] = valid ? s_s[row * SLD + r] * inv_scale : -INFINITY;
      mx = fmaxf(mx, e[i]);
    }
    mx = fmaxf(mx, __shfl_xor(mx, 1)); mx = fmaxf(mx, __shfl_xor(mx, 2));
    mx = fmaxf(mx, __shfl_xor(mx, 4)); mx = fmaxf(mx, __shfl_xor(mx, 8));
    float sum = 0.f;
#pragma unroll
    for (int i = 0; i < 5; ++i) {
      e[i] = (e[i] == -INFINITY) ? 0.f : __expf(e[i] - mx);
      sum += e[i];
    }
    sum += __shfl_xor(sum, 1); sum += __shfl_xor(sum, 2);
    sum += __shfl_xor(sum, 4); sum += __shfl_xor(sum, 8);
    const float rs = 1.f / sum;
#pragma unroll
    for (int i = 0; i < 5; ++i)
      p_s[row * PLD + li + 16 * i] = bf16_rn(e[i] * rs);
    if (li < 8) {
      p_s[row * PLD + 80 + li] = 0;
      p_s[row * PLD + 88 + li] = 0;
      p_s[row * PLD + 96 + li] = 0;
    }
  }
  __syncthreads();

  const ptrdiff_t mcol0 = (ptrdiff_t)b * TT + t0 - 32;
#pragma unroll 2
  for (int nt8 = 0; nt8 < 8; ++nt8) {
    const int nt = wave * 8 + nt8;
    const ushort* vrow = vT + (ptrdiff_t)(nt * 16 + mlane) * MM + mcol0;
    floatx4 o = (floatx4){0.f, 0.f, 0.f, 0.f};
#pragma unroll
    for (int ks = 0; ks < 3; ++ks) {
      short8 a  = *(const short8*)(&p_s[mlane * PLD + ks * 32 + quad * 8]);
      short8 bv = *(const short8*)(vrow + ks * 32 + quad * 8);
      o = __builtin_amdgcn_mfma_f32_16x16x32_bf16(a, bv, o, 0, 0, 0);
    }
#pragma unroll
    for (int r = 0; r < 4; ++r)
      out[(size_t)(bt0 + quad * 4 + r) * CC + nt * 16 + mlane] = bf16_rn(o[r]);
  }
}

// ---------------------------------------------------------------------------
extern "C" void kernel_launch(void* const* d_in, const int* in_sizes, int n_in,
                              void* d_out, int out_size, void* d_ws, size_t ws_size,
                              hipStream_t stream) {
  const float* x      = (const float*)d_in[0];
  const float* w_qkv  = (const float*)d_in[1];
  const float* b_qkv  = (const float*)d_in[2];
  const float* w_proj = (const float*)d_in[3];
  const float* b_proj = (const float*)d_in[4];
  float* outp = (float*)d_out;

  // ws layout (ushorts). 256 KB front guard absorbs attn's src<0 K-reads;
  // attn buffer right after qkv absorbs src>=TT K-read overruns.
  ushort* base  = (ushort*)d_ws;
  ushort* qkv   = base + 131072;                   // MM x 1536 (V third unused)
  ushort* attn  = qkv + (size_t)MM * 3 * CC;       // MM x 512
  ushort* xb    = attn + (size_t)MM * CC;          // MM x 512
  ushort* wqb   = xb + (size_t)NX;                 // 1536 x 512
  ushort* wpb   = wqb + (size_t)NWQ;               // 512 x 512
  ushort* vTg   = wpb + (size_t)NWP;               // guard(64) + 512 x 4096 + guard(64)
  ushort* vT    = vTg + 64;

  // 0) convert fp32 inputs to bf16
  convert_bf16<<<(NX + NWQ + NWP) / (256 * 8), 256, 0, stream>>>(x, w_qkv, w_proj, xb, wqb, wpb);
  // 1) qkv = x @ w_qkv.T + b_qkv -> Q,K bf16 rows; V written transposed to vT
  {
    dim3 grid((3 * CC) / 64, MM / 128);  // 24 x 32 = 768 blocks (%8==0, swizzled)
    gemm_panel<128, ushort><<<grid, 256, 0, stream>>>(xb, wqb, b_qkv, qkv, vT, MM, 3 * CC);
  }
  // 2) banded attention (bf16 -> bf16), LDS-free MFMA, 256 blocks (1/CU)
  attn_mfma<<<MM / ATILE, 256, 0, stream>>>(qkv, vT, attn);
  // 3) out = attn @ w_proj.T + b_proj -> fp32
  {
    dim3 grid(CC / 64, MM / 64);  // 8 x 64 = 512 blocks (%8==0, swizzled)
    gemm_panel<64, float><<<grid, 256, 0, stream>>>(attn, wpb, b_proj, outp, nullptr, MM, CC);
  }
}

// Round 5
// 107.389 us; speedup vs baseline: 1.0975x; 1.0302x over previous
//
#include <hip/hip_runtime.h>
#include <math.h>

// LocalAttention: B=2, T=2048, C=512, WINDOW=32
#define BB 2
#define TT 2048
#define CC 512
#define WIN 32
#define WSZ 63            // 2*WIN-1
#define MM (BB * TT)      // 4096

typedef __attribute__((ext_vector_type(8))) short short8;
typedef __attribute__((ext_vector_type(4))) float floatx4;

__device__ inline unsigned short bf16_rn(float f) {
  unsigned u = __builtin_bit_cast(unsigned, f);
  u += 0x7fff + ((u >> 16) & 1);
  return (unsigned short)(u >> 16);
}
__device__ inline unsigned pack_bf16x2(float lo, float hi) {
  return (unsigned)bf16_rn(lo) | ((unsigned)bf16_rn(hi) << 16);
}

// ---------------------------------------------------------------------------
// Pre-convert fp32 inputs -> bf16 (x, w_qkv, w_proj). 8 elems/thread.
// NOTE (R4 lesson): keep this stage. Steady-state kernels must consume ws
// copies refreshed every call, not d_in directly — the replay-invariance
// check diverged when gemms read fp32 inputs in the timed phase.
// ---------------------------------------------------------------------------
#define NX  (MM * CC)          // 2097152
#define NWQ (3 * CC * CC)      // 786432
#define NWP (CC * CC)          // 262144

__global__ __launch_bounds__(256) void convert_bf16(
    const float* __restrict__ x, const float* __restrict__ wq,
    const float* __restrict__ wp, ushort* __restrict__ xb,
    ushort* __restrict__ wqb, ushort* __restrict__ wpb) {
  const size_t e = ((size_t)blockIdx.x * 256 + threadIdx.x) * 8;
  const float* src;
  ushort* dst;
  size_t off;
  if (e < NX) { src = x; dst = xb; off = e; }
  else if (e < NX + NWQ) { src = wq; dst = wqb; off = e - NX; }
  else { src = wp; dst = wpb; off = e - NX - NWQ; }
  float4 v0 = ((const float4*)(src + off))[0];
  float4 v1 = ((const float4*)(src + off))[1];
  uint4 o;
  o.x = pack_bf16x2(v0.x, v0.y);
  o.y = pack_bf16x2(v0.z, v0.w);
  o.z = pack_bf16x2(v1.x, v1.y);
  o.w = pack_bf16x2(v1.z, v1.w);
  *(uint4*)(dst + off) = o;
}

// ---------------------------------------------------------------------------
// Barrier-light NT GEMM: C[m,n] = sum_k A[m,k]*B[n,k] + bias[n], K=512 fixed.
// Block = BM x 64. B-panel (64 n x 256 k) staged in LDS once per k-half ->
// only 3 barriers per block, NO per-K-step barrier/drain. A fragments are
// loaded directly from global (L1/L2-hot). 4 waves, each owns BM/4 m-rows
// and the full 64-n range.
// V path (VT != nullptr && n0 >= 1024): tile is bias-added, packed to bf16,
// transposed through LDS, and written as coalesced 256B rows of VT[n][m].
// ---------------------------------------------------------------------------
#define PSTR 264   // B-panel k-stride (elems); 528B rows -> 2-way banked frag reads
#define VSTR 136   // V-transpose m-stride (elems); 16B-aligned rows, odd granules

template <int BM, typename OT>
__global__ __launch_bounds__(256) void gemm_panel(
    const ushort* __restrict__ A, const ushort* __restrict__ B,
    const float* __restrict__ bias, OT* __restrict__ C,
    ushort* __restrict__ VT, int M, int N) {
  constexpr int MIW = BM / 64;                    // m-frags per wave (2 or 1)
  __shared__ __align__(16) ushort Bs[64 * PSTR];  // 33792 B; Vt aliases below

  const int tid = threadIdx.x;
  const int lane = tid & 63;
  const int wave = tid >> 6;
  const int m0 = blockIdx.y * BM;
  const int n0 = blockIdx.x * 64;
  const int wm = wave * (BM / 4);
  const int mlane = lane & 15, quad = lane >> 4;

  floatx4 acc[MIW][4];
#pragma unroll
  for (int i = 0; i < MIW; ++i)
#pragma unroll
    for (int j = 0; j < 4; ++j) acc[i][j] = (floatx4){0.f, 0.f, 0.f, 0.f};

  for (int h = 0; h < 2; ++h) {
    if (h) __syncthreads();
    // stage B panel half: 64 rows x 256 k = 2048 uint4, coalesced
#pragma unroll
    for (int i = 0; i < 8; ++i) {
      const int idx = tid + 256 * i;
      const int r = idx >> 5, kc = (idx & 31) * 8;
      *(uint4*)(&Bs[r * PSTR + kc]) =
          *(const uint4*)(B + (size_t)(n0 + r) * CC + h * 256 + kc);
    }
    __syncthreads();
#pragma unroll
    for (int ks = 0; ks < 8; ++ks) {
      short8 bfr[4];
#pragma unroll
      for (int ni = 0; ni < 4; ++ni)
        bfr[ni] = *(const short8*)(&Bs[(ni * 16 + mlane) * PSTR + ks * 32 + quad * 8]);
#pragma unroll
      for (int mi = 0; mi < MIW; ++mi) {
        short8 af = *(const short8*)(
            A + (size_t)(m0 + wm + mi * 16 + mlane) * CC + h * 256 + ks * 32 + quad * 8);
#pragma unroll
        for (int ni = 0; ni < 4; ++ni)
          acc[mi][ni] = __builtin_amdgcn_mfma_f32_16x16x32_bf16(af, bfr[ni], acc[mi][ni], 0, 0, 0);
      }
    }
  }

  // epilogue: D row = quad*4 + r (m), col = mlane (n)
  const bool vpath = (VT != nullptr) && (n0 >= 1024);
  if (!vpath) {
#pragma unroll
    for (int ni = 0; ni < 4; ++ni) {
      const int n = n0 + ni * 16 + mlane;
      const float bn = bias[n];
#pragma unroll
      for (int mi = 0; mi < MIW; ++mi) {
        const int mbase = m0 + wm + mi * 16 + quad * 4;
#pragma unroll
        for (int r = 0; r < 4; ++r) {
          float val = acc[mi][ni][r] + bn;
          if constexpr (sizeof(OT) == 2)
            ((ushort*)C)[(size_t)(mbase + r) * N + n] = bf16_rn(val);
          else
            ((float*)C)[(size_t)(mbase + r) * N + n] = val;
        }
      }
    }
  } else if constexpr (BM == 128) {
    // transpose through LDS, then coalesced VT[n][m] row writes
    ushort* Vt = Bs;  // alias; 64 x VSTR = 17408 B
    __syncthreads();
#pragma unroll
    for (int ni = 0; ni < 4; ++ni) {
      const int n_l = ni * 16 + mlane;
      const float bn = bias[n0 + n_l];
#pragma unroll
      for (int mi = 0; mi < MIW; ++mi) {
        const int m_l = wm + mi * 16 + quad * 4;
        ushort4 pk;
        pk.x = bf16_rn(acc[mi][ni][0] + bn);
        pk.y = bf16_rn(acc[mi][ni][1] + bn);
        pk.z = bf16_rn(acc[mi][ni][2] + bn);
        pk.w = bf16_rn(acc[mi][ni][3] + bn);
        *(ushort4*)(&Vt[n_l * VSTR + m_l]) = pk;
      }
    }
    __syncthreads();
#pragma unroll
    for (int i = 0; i < 4; ++i) {  // 64 rows x 16 uint4
      const int idx = tid + 256 * i;
      const int n_l = idx >> 4, mo = (idx & 15) * 8;
      *(uint4*)(VT + (size_t)(n0 - 1024 + n_l) * M + m0 + mo) =
          *(const uint4*)(&Vt[n_l * VSTR + mo]);
    }
  }
}

// ---------------------------------------------------------------------------
// LDS-free MFMA banded attention. Block = 16 tokens; the 16-row Q-tile needs
// a 16+62=78-key band <= the 80 columns computed. Grid 256 = 1 block/CU;
// XCD-bijective swizzle -> contiguous 512-token span per XCD (K-band/V-window
// overlaps between adjacent tiles are concurrent L2 hits).
// OOB reads fault-safe via ws guards; garbage lands in masked/P=0 positions.
// ---------------------------------------------------------------------------
#define ATILE 16
#define SLD 84    // S row stride (floats)
#define PLD 104   // P row stride (ushorts), odd granules -> conflict-free

__global__ __launch_bounds__(256) void attn_mfma(
    const ushort* __restrict__ qkv, const ushort* __restrict__ vT,
    ushort* __restrict__ out) {
  __shared__ __align__(16) float s_s[16 * SLD];
  __shared__ __align__(16) ushort p_s[16 * PLD];

  const int tid = threadIdx.x;
  const int wave = tid >> 6, lane = tid & 63;
  const int mlane = lane & 15, quad = lane >> 4;
  // XCD-bijective swizzle: 256 blocks, 8 XCDs, 32 tiles each (contiguous)
  const int tile = ((blockIdx.x & 7) << 5) | (blockIdx.x >> 3);
  const int bt0 = tile * ATILE;
  const int b = bt0 / TT, t0 = bt0 % TT;
  const ushort* qbase = qkv + (size_t)b * TT * (3 * CC);

  const ushort* qrow  = qbase + (ptrdiff_t)(t0 + mlane) * (3 * CC);
  const ushort* krow0 = qbase + (ptrdiff_t)(t0 - 32 + wave * 16 + mlane) * (3 * CC) + CC;
  const ushort* krow1 = qbase + (ptrdiff_t)(t0 - 32 + 64 + mlane) * (3 * CC) + CC;
  floatx4 sacc0 = (floatx4){0.f, 0.f, 0.f, 0.f};
  floatx4 sacc1 = (floatx4){0.f, 0.f, 0.f, 0.f};
#pragma unroll
  for (int ks = 0; ks < 16; ++ks) {
    short8 a  = *(const short8*)(qrow + ks * 32 + quad * 8);
    short8 b0 = *(const short8*)(krow0 + ks * 32 + quad * 8);
    sacc0 = __builtin_amdgcn_mfma_f32_16x16x32_bf16(a, b0, sacc0, 0, 0, 0);
    if (wave == 0) {
      short8 b1 = *(const short8*)(krow1 + ks * 32 + quad * 8);
      sacc1 = __builtin_amdgcn_mfma_f32_16x16x32_bf16(a, b1, sacc1, 0, 0, 0);
    }
  }

#pragma unroll
  for (int r = 0; r < 4; ++r)
    s_s[(quad * 4 + r) * SLD + wave * 16 + mlane] = sacc0[r];
  if (wave == 0) {
#pragma unroll
    for (int r = 0; r < 4; ++r)
      s_s[(quad * 4 + r) * SLD + 64 + mlane] = sacc1[r];
  }
  __syncthreads();

  {
    const int row = tid >> 4, li = tid & 15;
    const float inv_scale = 0.044194173824159216f;  // 512^-0.5
    float e[5];
    float mx = -INFINITY;
#pragma unroll
    for (int i = 0; i < 5; ++i) {
      const int r = li + 16 * i;
      const int j = r - 1 - row;
      const int src = t0 - 32 + r;
      const bool valid = (j >= 0) && (j < WSZ) && (src >= 0) && (src < TT);
      e[i] = valid ? s_s[row * SLD + r] * inv_scale : -INFINITY;
      mx = fmaxf(mx, e[i]);
    }
    mx = fmaxf(mx, __shfl_xor(mx, 1)); mx = fmaxf(mx, __shfl_xor(mx, 2));
    mx = fmaxf(mx, __shfl_xor(mx, 4)); mx = fmaxf(mx, __shfl_xor(mx, 8));
    float sum = 0.f;
#pragma unroll
    for (int i = 0; i < 5; ++i) {
      e[i] = (e[i] == -INFINITY) ? 0.f : __expf(e[i] - mx);
      sum += e[i];
    }
    sum += __shfl_xor(sum, 1); sum += __shfl_xor(sum, 2);
    sum += __shfl_xor(sum, 4); sum += __shfl_xor(sum, 8);
    const float rs = 1.f / sum;
#pragma unroll
    for (int i = 0; i < 5; ++i)
      p_s[row * PLD + li + 16 * i] = bf16_rn(e[i] * rs);
    if (li < 8) {
      p_s[row * PLD + 80 + li] = 0;
      p_s[row * PLD + 88 + li] = 0;
      p_s[row * PLD + 96 + li] = 0;
    }
  }
  __syncthreads();

  // P fragments are nt8-invariant: hoist the 3 LDS reads out of the PV loop.
  short8 pa[3];
#pragma unroll
  for (int ks = 0; ks < 3; ++ks)
    pa[ks] = *(const short8*)(&p_s[mlane * PLD + ks * 32 + quad * 8]);

  const ptrdiff_t mcol0 = (ptrdiff_t)b * TT + t0 - 32;
#pragma unroll 2
  for (int nt8 = 0; nt8 < 8; ++nt8) {
    const int nt = wave * 8 + nt8;
    const ushort* vrow = vT + (ptrdiff_t)(nt * 16 + mlane) * MM + mcol0;
    floatx4 o = (floatx4){0.f, 0.f, 0.f, 0.f};
#pragma unroll
    for (int ks = 0; ks < 3; ++ks) {
      short8 bv = *(const short8*)(vrow + ks * 32 + quad * 8);
      o = __builtin_amdgcn_mfma_f32_16x16x32_bf16(pa[ks], bv, o, 0, 0, 0);
    }
#pragma unroll
    for (int r = 0; r < 4; ++r)
      out[(size_t)(bt0 + quad * 4 + r) * CC + nt * 16 + mlane] = bf16_rn(o[r]);
  }
}

// ---------------------------------------------------------------------------
extern "C" void kernel_launch(void* const* d_in, const int* in_sizes, int n_in,
                              void* d_out, int out_size, void* d_ws, size_t ws_size,
                              hipStream_t stream) {
  const float* x      = (const float*)d_in[0];
  const float* w_qkv  = (const float*)d_in[1];
  const float* b_qkv  = (const float*)d_in[2];
  const float* w_proj = (const float*)d_in[3];
  const float* b_proj = (const float*)d_in[4];
  float* outp = (float*)d_out;

  // ws layout (ushorts). 256 KB front guard absorbs attn's src<0 K-reads;
  // attn buffer right after qkv absorbs src>=TT K-read overruns.
  ushort* base  = (ushort*)d_ws;
  ushort* qkv   = base + 131072;                   // MM x 1536 (V third unused)
  ushort* attn  = qkv + (size_t)MM * 3 * CC;       // MM x 512
  ushort* xb    = attn + (size_t)MM * CC;          // MM x 512
  ushort* wqb   = xb + (size_t)NX;                 // 1536 x 512
  ushort* wpb   = wqb + (size_t)NWQ;               // 512 x 512
  ushort* vTg   = wpb + (size_t)NWP;               // guard(64) + 512 x 4096 + guard(64)
  ushort* vT    = vTg + 64;

  // 0) convert fp32 inputs to bf16
  convert_bf16<<<(NX + NWQ + NWP) / (256 * 8), 256, 0, stream>>>(x, w_qkv, w_proj, xb, wqb, wpb);
  // 1) qkv = x @ w_qkv.T + b_qkv -> Q,K bf16 rows; V written transposed to vT
  {
    dim3 grid((3 * CC) / 64, MM / 128);  // 24 x 32 = 768 blocks
    gemm_panel<128, ushort><<<grid, 256, 0, stream>>>(xb, wqb, b_qkv, qkv, vT, MM, 3 * CC);
  }
  // 2) banded attention (bf16 -> bf16), LDS-free MFMA, 256 blocks (1/CU)
  attn_mfma<<<MM / ATILE, 256, 0, stream>>>(qkv, vT, attn);
  // 3) out = attn @ w_proj.T + b_proj -> fp32
  {
    dim3 grid(CC / 64, MM / 64);  // 8 x 64 = 512 blocks
    gemm_panel<64, float><<<grid, 256, 0, stream>>>(attn, wpb, b_proj, outp, nullptr, MM, CC);
  }
}